// Round 1
// baseline (665.337 us; speedup 1.0000x reference)
//
#include <hip/hip_runtime.h>
#include <stdint.h>

typedef unsigned short u16;
typedef __bf16 bf16x8 __attribute__((ext_vector_type(8)));
typedef float f32x4 __attribute__((ext_vector_type(4)));

#define MFMA16(a, b, c) __builtin_amdgcn_mfma_f32_16x16x32_bf16((a), (b), (c), 0, 0, 0)

// ---- constants -------------------------------------------------------------
#define BB 64
#define SS 200
#define DM 1024
#define NH 16
#define DKK 64
#define MM (BB * SS)          // 12800
#define OUT0_ELEMS (MM * DM)  // 13107200

// ---- helpers ---------------------------------------------------------------
__device__ static inline u16 f2bf(float f) {
    __bf16 h = (__bf16)f;                 // RNE convert
    return __builtin_bit_cast(u16, h);
}

__device__ static inline bf16x8 load8(const u16* p) {
    uint4 u = *(const uint4*)p;           // 16B vector load
    union { uint4 u; bf16x8 b; } cv; cv.u = u; return cv.b;
}

__device__ static inline bf16x8 bzero8() {
    union { uint4 u; bf16x8 b; } cv; cv.u = make_uint4(0u, 0u, 0u, 0u); return cv.b;
}

__device__ static inline void gload_lds16(const void* g, void* l) {
    __builtin_amdgcn_global_load_lds(
        (const __attribute__((address_space(1))) void*)g,
        (__attribute__((address_space(3))) void*)l, 16, 0, 0);
}

// ---- kernel 1: f32 -> bf16 conversion (x + 4 weight matrices) --------------
__global__ __launch_bounds__(256) void convert_k(
    const float* __restrict__ x,
    const float* __restrict__ wq, const float* __restrict__ wk,
    const float* __restrict__ wv, const float* __restrict__ wo,
    u16* __restrict__ xb,
    u16* __restrict__ wqb, u16* __restrict__ wkb,
    u16* __restrict__ wvb, u16* __restrict__ wob)
{
    size_t i4 = (size_t)blockIdx.x * 256 + threadIdx.x;
    size_t e = i4 * 4;
    const float* src; u16* dst; size_t off;
    if (e < (size_t)OUT0_ELEMS) { src = x; dst = xb; off = e; }
    else {
        size_t we = e - OUT0_ELEMS;
        size_t w = we >> 20;              // each weight = 1048576 elems
        off = we & 1048575u;
        src = (w == 0) ? wq : (w == 1) ? wk : (w == 2) ? wv : wo;
        dst = (w == 0) ? wqb : (w == 1) ? wkb : (w == 2) ? wvb : wob;
    }
    float4 v = *(const float4*)(src + off);
    union { u16 s[4]; uint2 u; } o;
    o.s[0] = f2bf(v.x); o.s[1] = f2bf(v.y); o.s[2] = f2bf(v.z); o.s[3] = f2bf(v.w);
    *(uint2*)(dst + off) = o.u;
}

// ---- kernel 2/4: 128x128 MFMA GEMM, A[M,1024] bf16 * W[N,1024]^T ----------
// MODE 0: z in {0,1,2} selects q/k/v; epilogue adds bias, writes bf16:
//   q,k -> [b,h,s,dk]   v -> [b,h,dk,s] (transposed for PV B-operand)
// MODE 1: out-proj; epilogue adds bias, writes f32 row-major [M,1024].
template <int MODE>
__global__ __launch_bounds__(256) void gemm_k(
    const u16* __restrict__ A,
    const u16* __restrict__ W0, const u16* __restrict__ W1, const u16* __restrict__ W2,
    const float* __restrict__ b0, const float* __restrict__ b1, const float* __restrict__ b2,
    u16* __restrict__ qo, u16* __restrict__ ko, u16* __restrict__ vto,
    float* __restrict__ outf)
{
    __shared__ __align__(16) u16 As[128 * 32];
    __shared__ __align__(16) u16 Bs[128 * 32];

    const int tid  = threadIdx.x;
    const int wave = tid >> 6;
    const int lane = tid & 63;
    const int quad = lane >> 4;
    const int l15  = lane & 15;
    const int n0   = blockIdx.x * 128;
    const int m0   = blockIdx.y * 128;
    const int z    = (MODE == 0) ? blockIdx.z : 0;

    const u16* W = (MODE == 1) ? W0 : (z == 0 ? W0 : (z == 1 ? W1 : W2));
    const float* bias = (MODE == 1) ? b0 : (z == 0 ? b0 : (z == 1 ? b1 : b2));

    const int srow = wave * 16 + (lane >> 2); // row within a 64-row half
    const int sk8  = (lane & 3) * 8;          // k-elem offset 0/8/16/24
    const int wuni = __builtin_amdgcn_readfirstlane(wave);

    f32x4 acc[4][4];
#pragma unroll
    for (int i = 0; i < 4; i++)
#pragma unroll
        for (int j = 0; j < 4; j++) acc[i][j] = (f32x4){0.f, 0.f, 0.f, 0.f};

    const int wr = (wave >> 1) * 64;  // wave row offset in 128-tile
    const int wc = (wave & 1) * 64;   // wave col offset

    const u16* Ag = A + (size_t)m0 * 1024;
    const u16* Wg = W + (size_t)n0 * 1024;

    for (int kc = 0; kc < 1024; kc += 32) {
        __syncthreads();
#pragma unroll
        for (int r = 0; r < 2; r++) {
            int row = r * 64 + srow;
            gload_lds16(Ag + (size_t)row * 1024 + kc + sk8, &As[(r * 64 + wuni * 16) * 32]);
        }
#pragma unroll
        for (int r = 0; r < 2; r++) {
            int row = r * 64 + srow;
            gload_lds16(Wg + (size_t)row * 1024 + kc + sk8, &Bs[(r * 64 + wuni * 16) * 32]);
        }
        __syncthreads();

        bf16x8 af[4], bf[4];
#pragma unroll
        for (int mt = 0; mt < 4; mt++) af[mt] = load8(&As[(wr + mt * 16 + l15) * 32 + quad * 8]);
#pragma unroll
        for (int nt = 0; nt < 4; nt++) bf[nt] = load8(&Bs[(wc + nt * 16 + l15) * 32 + quad * 8]);
#pragma unroll
        for (int mt = 0; mt < 4; mt++)
#pragma unroll
            for (int nt = 0; nt < 4; nt++)
                acc[mt][nt] = MFMA16(af[mt], bf[nt], acc[mt][nt]);
    }

    // epilogue  (C layout: col = lane&15, row = quad*4 + reg)
#pragma unroll
    for (int nt = 0; nt < 4; nt++) {
        int n = n0 + wc + nt * 16 + l15;
        float bv = bias[n];
#pragma unroll
        for (int mt = 0; mt < 4; mt++) {
#pragma unroll
            for (int r = 0; r < 4; r++) {
                int m = m0 + wr + mt * 16 + quad * 4 + r;
                float val = acc[mt][nt][r] + bv;
                if (MODE == 0) {
                    int b = m / 200, s = m - b * 200;
                    int h = n >> 6, d = n & 63;
                    size_t bh = (size_t)(b * 16 + h);
                    if (z == 0)      qo[(bh * 200 + s) * 64 + d] = f2bf(val);
                    else if (z == 1) ko[(bh * 200 + s) * 64 + d] = f2bf(val);
                    else             vto[(bh * 64 + d) * 200 + s] = f2bf(val);
                } else {
                    outf[(size_t)m * 1024 + n] = val;
                }
            }
        }
    }
}

// ---- kernel 3: fused attention per (b,h): QK^T + bias + mask + softmax
//      + attn f32 writeout + PV -> ctx bf16 [b,s,h*64+d] ----------------------
__global__ __launch_bounds__(256) void attn_k(
    const u16* __restrict__ qg, const u16* __restrict__ kg, const u16* __restrict__ vt,
    const float* __restrict__ tb, const int* __restrict__ mask,
    float* __restrict__ attn_out, u16* __restrict__ ctxb)
{
    __shared__ __align__(16) u16 Ap[4 * 16 * 224];  // per-wave attn tile, j padded to 224

    const int tid  = threadIdx.x;
    const int wave = tid >> 6;
    const int lane = tid & 63;
    const int quad = lane >> 4;
    const int l15  = lane & 15;
    const int bh   = blockIdx.y;
    const int b    = bh >> 4;
    const int h    = bh & 15;
    const int i0   = blockIdx.x * 64 + wave * 16;

    const u16* qp = qg + (size_t)bh * 200 * 64;
    const u16* kp = kg + (size_t)bh * 200 * 64;

    // A-frags (q rows), reused across all j-tiles
    int qi = i0 + l15;
    bf16x8 aq0, aq1;
    if (qi < 200) {
        aq0 = load8(qp + qi * 64 + quad * 8);
        aq1 = load8(qp + qi * 64 + 32 + quad * 8);
    } else { aq0 = bzero8(); aq1 = bzero8(); }

    // scores: 13 tiles of 16 cols (208 >= 200)
    f32x4 sc[13];
#pragma unroll
    for (int t = 0; t < 13; t++) {
        int kj = t * 16 + l15;
        bf16x8 bk0, bk1;
        if (kj < 200) {
            bk0 = load8(kp + kj * 64 + quad * 8);
            bk1 = load8(kp + kj * 64 + 32 + quad * 8);
        } else { bk0 = bzero8(); bk1 = bzero8(); }
        f32x4 zz = (f32x4){0.f, 0.f, 0.f, 0.f};
        zz = MFMA16(aq0, bk0, zz);
        zz = MFMA16(aq1, bk1, zz);
        sc[t] = zz;
    }

    // bias + mask + row max   (C layout: row i = i0 + quad*4 + r, col j = t*16 + l15)
    const int ibase = i0 + quad * 4;
    const float* tbp = tb + (size_t)h * 40000 + (size_t)ibase * 200 + l15;
    const int*   mkp = mask + (size_t)b * 40000 + (size_t)ibase * 200 + l15;

    float mx[4] = {-3e38f, -3e38f, -3e38f, -3e38f};
#pragma unroll
    for (int t = 0; t < 13; t++) {
#pragma unroll
        for (int r = 0; r < 4; r++) {
            int i = ibase + r, j = t * 16 + l15;
            float s;
            if (i < 200 && j < 200) {
                s = sc[t][r] * 0.125f + tbp[r * 200 + t * 16];
                if (mkp[r * 200 + t * 16] == 0) s = -1e9f;
            } else s = -3e38f;
            sc[t][r] = s;
            mx[r] = fmaxf(mx[r], s);
        }
    }
#pragma unroll
    for (int r = 0; r < 4; r++)
        for (int m = 1; m < 16; m <<= 1) mx[r] = fmaxf(mx[r], __shfl_xor(mx[r], m, 64));

    float sum[4] = {0.f, 0.f, 0.f, 0.f};
#pragma unroll
    for (int t = 0; t < 13; t++) {
#pragma unroll
        for (int r = 0; r < 4; r++) {
            int i = ibase + r, j = t * 16 + l15;
            float e = (i < 200 && j < 200) ? __expf(sc[t][r] - mx[r]) : 0.f;
            sc[t][r] = e;
            sum[r] += e;
        }
    }
#pragma unroll
    for (int r = 0; r < 4; r++)
        for (int m = 1; m < 16; m <<= 1) sum[r] += __shfl_xor(sum[r], m, 64);

    float inv[4];
#pragma unroll
    for (int r = 0; r < 4; r++) inv[r] = (sum[r] > 0.f) ? 1.f / sum[r] : 0.f;

    // write attn (f32 -> d_out) and stage bf16 attn into LDS (A-operand layout source)
    u16* lp = &Ap[wave * 16 * 224];
    float* aop = attn_out + ((size_t)bh * 200 + ibase) * 200 + l15;
#pragma unroll
    for (int t = 0; t < 13; t++) {
#pragma unroll
        for (int r = 0; r < 4; r++) {
            int i = ibase + r, j = t * 16 + l15;
            float a = sc[t][r] * inv[r];
            lp[(quad * 4 + r) * 224 + j] = f2bf(a);   // j>=200 entries are 0 (e==0)
            if (i < 200 && j < 200) aop[r * 200 + t * 16] = a;
        }
    }
#pragma unroll
    for (int r = 0; r < 4; r++) lp[(quad * 4 + r) * 224 + 208 + l15] = 0;  // pad 208..223
    __syncthreads();

    // PV: ctx[16 x 64] = attn[16 x 224] * vt[64 x 200(+pad)]
    f32x4 ctx[4];
#pragma unroll
    for (int nt = 0; nt < 4; nt++) ctx[nt] = (f32x4){0.f, 0.f, 0.f, 0.f};
    const u16* vtb = vt + (size_t)bh * 64 * 200;
#pragma unroll
    for (int kc = 0; kc < 224; kc += 32) {
        bf16x8 af = load8(lp + l15 * 224 + kc + quad * 8);
        int j0 = kc + quad * 8;
#pragma unroll
        for (int nt = 0; nt < 4; nt++) {
            bf16x8 bv = (j0 < 200) ? load8(vtb + (nt * 16 + l15) * 200 + j0) : bzero8();
            ctx[nt] = MFMA16(af, bv, ctx[nt]);
        }
    }

    // ctx -> [b, i, h*64 + d] bf16
#pragma unroll
    for (int nt = 0; nt < 4; nt++) {
#pragma unroll
        for (int r = 0; r < 4; r++) {
            int i = ibase + r;
            if (i < 200)
                ctxb[((size_t)b * 200 + i) * 1024 + h * 64 + nt * 16 + l15] = f2bf(ctx[nt][r]);
        }
    }
}

// ---- launch ----------------------------------------------------------------
extern "C" void kernel_launch(void* const* d_in, const int* in_sizes, int n_in,
                              void* d_out, int out_size, void* d_ws, size_t ws_size,
                              hipStream_t stream) {
    const float* x    = (const float*)d_in[0];
    const int*   mask = (const int*)d_in[1];
    const float* wq   = (const float*)d_in[2];
    const float* bq   = (const float*)d_in[3];
    const float* wk   = (const float*)d_in[4];
    const float* bk   = (const float*)d_in[5];
    const float* wv   = (const float*)d_in[6];
    const float* bv   = (const float*)d_in[7];
    const float* wo   = (const float*)d_in[8];
    const float* bo   = (const float*)d_in[9];
    const float* tb   = (const float*)d_in[10];

    float* out  = (float*)d_out;
    float* attn = out + OUT0_ELEMS;

    char* ws = (char*)d_ws;
    u16* xb   = (u16*)(ws);                    // 26,214,400 B
    u16* wqb  = (u16*)(ws + 26214400);         //  2,097,152 B
    u16* wkb  = (u16*)(ws + 28311552);
    u16* wvb  = (u16*)(ws + 30408704);
    u16* wob  = (u16*)(ws + 32505856);
    u16* qb   = (u16*)(ws + 34603008);         // 26,214,400 B  [b,h,s,dk]
    u16* kb   = (u16*)(ws + 60817408);         // 26,214,400 B
    u16* vtb  = (u16*)(ws + 87031808);         // 26,214,400 B  [b,h,dk,s]
    u16* ctxb = (u16*)(ws + 113246208);        // 26,214,400 B  [b,s,h*dk]
    // total: 139,460,608 B

    // 1) convert x + weights to bf16: (13107200 + 4*1048576)/4 / 256 = 16896 blocks
    convert_k<<<dim3(16896), dim3(256), 0, stream>>>(x, wq, wk, wv, wo, xb, wqb, wkb, wvb, wob);

    // 2) QKV projections: M=12800 (100 tiles) x N=1024 (8 tiles) x 3
    gemm_k<0><<<dim3(8, 100, 3), dim3(256), 0, stream>>>(
        xb, wqb, wkb, wvb, bq, bk, bv, qb, kb, vtb, nullptr);

    // 3) fused attention: 4 row-tiles x (B*H = 1024)
    attn_k<<<dim3(4, 1024), dim3(256), 0, stream>>>(qb, kb, vtb, tb, mask, attn, ctxb);

    // 4) output projection
    gemm_k<1><<<dim3(8, 100, 1), dim3(256), 0, stream>>>(
        ctxb, wob, nullptr, nullptr, bo, nullptr, nullptr, nullptr, nullptr, nullptr, out);
}

// Round 2
// 587.619 us; speedup vs baseline: 1.1323x; 1.1323x over previous
//
#include <hip/hip_runtime.h>
#include <stdint.h>

typedef unsigned short u16;
typedef unsigned long long u64;
typedef __bf16 bf16x8 __attribute__((ext_vector_type(8)));
typedef float f32x4 __attribute__((ext_vector_type(4)));

#define MFMA16(a, b, c) __builtin_amdgcn_mfma_f32_16x16x32_bf16((a), (b), (c), 0, 0, 0)

// ---- constants -------------------------------------------------------------
#define BB 64
#define SS 200
#define DM 1024
#define NH 16
#define MM (BB * SS)          // 12800
#define OUT0_ELEMS (MM * DM)  // 13107200

// ---- helpers ---------------------------------------------------------------
__device__ static inline u16 f2bf(float f) {
    __bf16 h = (__bf16)f;                 // RNE convert
    return __builtin_bit_cast(u16, h);
}

__device__ static inline bf16x8 load8(const u16* p) {
    uint4 u = *(const uint4*)p;           // 16B vector load
    union { uint4 u; bf16x8 b; } cv; cv.u = u; return cv.b;
}

__device__ static inline bf16x8 bzero8() {
    union { uint4 u; bf16x8 b; } cv; cv.u = make_uint4(0u, 0u, 0u, 0u); return cv.b;
}

__device__ static inline void gload_lds16(const void* g, void* l) {
    __builtin_amdgcn_global_load_lds(
        (const __attribute__((address_space(1))) void*)g,
        (__attribute__((address_space(3))) void*)l, 16, 0, 0);
}

// ---- kernel 1: f32 -> bf16 conversion (x + 4 weight matrices) --------------
__global__ __launch_bounds__(256) void convert_k(
    const float* __restrict__ x,
    const float* __restrict__ wq, const float* __restrict__ wk,
    const float* __restrict__ wv, const float* __restrict__ wo,
    u16* __restrict__ xb,
    u16* __restrict__ wqb, u16* __restrict__ wkb,
    u16* __restrict__ wvb, u16* __restrict__ wob)
{
    size_t i4 = (size_t)blockIdx.x * 256 + threadIdx.x;
    size_t e = i4 * 4;
    const float* src; u16* dst; size_t off;
    if (e < (size_t)OUT0_ELEMS) { src = x; dst = xb; off = e; }
    else {
        size_t we = e - OUT0_ELEMS;
        size_t w = we >> 20;              // each weight = 1048576 elems
        off = we & 1048575u;
        src = (w == 0) ? wq : (w == 1) ? wk : (w == 2) ? wv : wo;
        dst = (w == 0) ? wqb : (w == 1) ? wkb : (w == 2) ? wvb : wob;
    }
    float4 v = *(const float4*)(src + off);
    union { u16 s[4]; uint2 u; } o;
    o.s[0] = f2bf(v.x); o.s[1] = f2bf(v.y); o.s[2] = f2bf(v.z); o.s[3] = f2bf(v.w);
    *(uint2*)(dst + off) = o.u;
}

// ---- kernel 1b: mask [64,1,200,200] int32 -> bit-packed 4 u64 per row ------
__global__ __launch_bounds__(256) void maskbits_k(
    const int* __restrict__ mask, u64* __restrict__ bits)
{
    __shared__ unsigned char nb[4][64];
    const int wave = threadIdx.x >> 6, lane = threadIdx.x & 63;
    const int row = blockIdx.x * 4 + wave;       // 0..12799 = b*200 + i
    if (row >= MM / DM * 0 + BB * SS) { /* never */ }
    const int* mp = mask + (size_t)row * 200;
    unsigned nib;
    if (lane < 50) {
        int4 v = *(const int4*)(mp + lane * 4);
        nib = (v.x ? 1u : 0u) | (v.y ? 2u : 0u) | (v.z ? 4u : 0u) | (v.w ? 8u : 0u);
    } else nib = 0xFu;                           // cols >= 200: unmasked (never used)
    nb[wave][lane] = (unsigned char)nib;
    __builtin_amdgcn_s_waitcnt(0);               // lgkm drain (same-wave ordering)
    if (lane < 4) {
        const unsigned char* p = &nb[wave][lane * 16];
        u64 m = 0;
#pragma unroll
        for (int i = 0; i < 16; i++) m |= (u64)(p[i] & 0xFu) << (4 * i);
        bits[(size_t)row * 4 + lane] = m;
    }
}

// ---- kernel 2/5: 128x128 MFMA GEMM, A[M,1024] bf16 * W[N,1024]^T ----------
// MODE 0: z in {0,1,2} selects q/k/v; epilogue adds bias, writes bf16:
//   q,k -> [b,h,s,dk]   v -> [b,h,dk,s] (transposed, vectorized uint2 stores)
// MODE 1: out-proj; epilogue adds bias, writes f32 row-major [M,1024].
template <int MODE>
__global__ __launch_bounds__(256) void gemm_k(
    const u16* __restrict__ A,
    const u16* __restrict__ W0, const u16* __restrict__ W1, const u16* __restrict__ W2,
    const float* __restrict__ b0, const float* __restrict__ b1, const float* __restrict__ b2,
    u16* __restrict__ qo, u16* __restrict__ ko, u16* __restrict__ vto,
    float* __restrict__ outf)
{
    __shared__ __align__(16) u16 As[128 * 32];
    __shared__ __align__(16) u16 Bs[128 * 32];

    const int tid  = threadIdx.x;
    const int wave = tid >> 6;
    const int lane = tid & 63;
    const int quad = lane >> 4;
    const int l15  = lane & 15;
    const int n0   = blockIdx.x * 128;
    const int m0   = blockIdx.y * 128;
    const int z    = (MODE == 0) ? blockIdx.z : 0;

    const u16* W = (MODE == 1) ? W0 : (z == 0 ? W0 : (z == 1 ? W1 : W2));
    const float* bias = (MODE == 1) ? b0 : (z == 0 ? b0 : (z == 1 ? b1 : b2));

    const int srow = wave * 16 + (lane >> 2); // row within a 64-row half
    const int sk8  = (lane & 3) * 8;          // k-elem offset 0/8/16/24
    const int wuni = __builtin_amdgcn_readfirstlane(wave);

    f32x4 acc[4][4];
#pragma unroll
    for (int i = 0; i < 4; i++)
#pragma unroll
        for (int j = 0; j < 4; j++) acc[i][j] = (f32x4){0.f, 0.f, 0.f, 0.f};

    const int wr = (wave >> 1) * 64;  // wave row offset in 128-tile
    const int wc = (wave & 1) * 64;   // wave col offset

    const u16* Ag = A + (size_t)m0 * 1024;
    const u16* Wg = W + (size_t)n0 * 1024;

    for (int kc = 0; kc < 1024; kc += 32) {
        __syncthreads();
#pragma unroll
        for (int r = 0; r < 2; r++) {
            int row = r * 64 + srow;
            gload_lds16(Ag + (size_t)row * 1024 + kc + sk8, &As[(r * 64 + wuni * 16) * 32]);
        }
#pragma unroll
        for (int r = 0; r < 2; r++) {
            int row = r * 64 + srow;
            gload_lds16(Wg + (size_t)row * 1024 + kc + sk8, &Bs[(r * 64 + wuni * 16) * 32]);
        }
        __syncthreads();

        bf16x8 af[4], bf[4];
#pragma unroll
        for (int mt = 0; mt < 4; mt++) af[mt] = load8(&As[(wr + mt * 16 + l15) * 32 + quad * 8]);
#pragma unroll
        for (int nt = 0; nt < 4; nt++) bf[nt] = load8(&Bs[(wc + nt * 16 + l15) * 32 + quad * 8]);
#pragma unroll
        for (int mt = 0; mt < 4; mt++)
#pragma unroll
            for (int nt = 0; nt < 4; nt++)
                acc[mt][nt] = MFMA16(af[mt], bf[nt], acc[mt][nt]);
    }

    // epilogue  (C layout: col = lane&15, row = quad*4 + reg)
#pragma unroll
    for (int nt = 0; nt < 4; nt++) {
        int n = n0 + wc + nt * 16 + l15;
        float bv = bias[n];
#pragma unroll
        for (int mt = 0; mt < 4; mt++) {
            if (MODE == 0 && z == 2) {
                // lane holds 4 consecutive m (=s) at fixed n: pack one uint2.
                // s % 4 == 0 and 200 % 4 == 0 -> never crosses a batch boundary.
                int mbase = m0 + wr + mt * 16 + quad * 4;
                int b = mbase / 200, s = mbase - b * 200;
                int hh = n >> 6, d = n & 63;
                union { u16 q[4]; uint2 u; } pk;
#pragma unroll
                for (int r = 0; r < 4; r++) pk.q[r] = f2bf(acc[mt][nt][r] + bv);
                *(uint2*)&vto[((size_t)(b * 16 + hh) * 64 + d) * 200 + s] = pk.u;
            } else {
#pragma unroll
                for (int r = 0; r < 4; r++) {
                    int m = m0 + wr + mt * 16 + quad * 4 + r;
                    float val = acc[mt][nt][r] + bv;
                    if (MODE == 0) {
                        int b = m / 200, s = m - b * 200;
                        int hh = n >> 6, d = n & 63;
                        size_t bhid = (size_t)(b * 16 + hh);
                        if (z == 0) qo[(bhid * 200 + s) * 64 + d] = f2bf(val);
                        else        ko[(bhid * 200 + s) * 64 + d] = f2bf(val);
                    } else {
                        outf[(size_t)m * 1024 + n] = val;
                    }
                }
            }
        }
    }
}

// ---- kernel 3: fused attention per (bh, 16-row wave tile) ------------------
// Phase A: QK^T MFMA -> f32 LDS (C-layout transpose buffer)
// Phase B: row-linear lanes (4/row): bias+mask+softmax, coalesced float4 tb
//          loads and attn f32 stores; bf16 attn tile -> LDS
// Phase C: PV MFMA from LDS A-frags + global vt B-frags; coalesced ctx out
__global__ __launch_bounds__(256) void attn_k(
    const u16* __restrict__ qg, const u16* __restrict__ kg, const u16* __restrict__ vtg,
    const float* __restrict__ tb, const u64* __restrict__ mbits,
    float* __restrict__ attn_out, u16* __restrict__ ctxb)
{
    __shared__ __align__(16) float Sf[4][16 * 212];   // 13568 B / wave
    __shared__ __align__(16) u16  Pb[4][16 * 208];    //  6656 B / wave  (total 80896)

    const int tid  = threadIdx.x;
    const int wave = tid >> 6;
    const int lane = tid & 63;
    const int quad = lane >> 4;
    const int l15  = lane & 15;
    const int bh   = blockIdx.y;
    const int b    = bh >> 4;
    const int h    = bh & 15;
    const int i0   = blockIdx.x * 64 + wave * 16;
    if (i0 >= 200) return;                            // whole-wave uniform, no barriers used

    const u16* qp = qg + (size_t)bh * 200 * 64;
    const u16* kp = kg + (size_t)bh * 200 * 64;
    float* sf = Sf[wave];
    u16*   pb = Pb[wave];

    // ---- phase A: scores -> Sf (C layout: row = quad*4+r, col = t*16+l15)
    int qi = i0 + l15;
    bf16x8 aq0, aq1;
    if (qi < 200) {
        aq0 = load8(qp + qi * 64 + quad * 8);
        aq1 = load8(qp + qi * 64 + 32 + quad * 8);
    } else { aq0 = bzero8(); aq1 = bzero8(); }

#pragma unroll
    for (int t = 0; t < 13; t++) {
        int kj = t * 16 + l15;
        bf16x8 bk0, bk1;
        if (kj < 200) {
            bk0 = load8(kp + kj * 64 + quad * 8);
            bk1 = load8(kp + kj * 64 + 32 + quad * 8);
        } else { bk0 = bzero8(); bk1 = bzero8(); }
        f32x4 z = (f32x4){0.f, 0.f, 0.f, 0.f};
        z = MFMA16(aq0, bk0, z);
        z = MFMA16(aq1, bk1, z);
#pragma unroll
        for (int r = 0; r < 4; r++) sf[(quad * 4 + r) * 212 + t * 16 + l15] = z[r];
    }

    // ---- phase B: row-linear (row = lane>>2, sub = lane&3; 4 lanes per row)
    const int row = lane >> 2, sub = lane & 3;
    const int iabs = i0 + row;
    const bool rowok = iabs < 200;
    const int irow = rowok ? iabs : 0;
    const u64* mb = mbits + ((size_t)b * 200 + irow) * 4;
    ulonglong2 mA = *(const ulonglong2*)mb;
    ulonglong2 mB = *(const ulonglong2*)(mb + 2);
    const float* tbrow = tb + (size_t)h * 40000 + (size_t)irow * 200;

    f32x4 sv[13];
    float mx = -3.0e38f;
#pragma unroll
    for (int c = 0; c < 13; c++) {
        int col = c * 16 + sub * 4;
        f32x4 s = *(const f32x4*)&sf[row * 212 + col];
        if (rowok && col < 200) {
            float4 tv = *(const float4*)(tbrow + col);
            u64 ch = (col < 64) ? mA.x : (col < 128) ? mA.y : (col < 192) ? mB.x : mB.y;
            int sh = col & 63;
            s[0] = s[0] * 0.125f + tv.x; if (!((ch >> (sh + 0)) & 1)) s[0] = -1e9f;
            s[1] = s[1] * 0.125f + tv.y; if (!((ch >> (sh + 1)) & 1)) s[1] = -1e9f;
            s[2] = s[2] * 0.125f + tv.z; if (!((ch >> (sh + 2)) & 1)) s[2] = -1e9f;
            s[3] = s[3] * 0.125f + tv.w; if (!((ch >> (sh + 3)) & 1)) s[3] = -1e9f;
        } else { s[0] = s[1] = s[2] = s[3] = -3.0e38f; }
        sv[c] = s;
        mx = fmaxf(mx, fmaxf(fmaxf(s[0], s[1]), fmaxf(s[2], s[3])));
    }
    mx = fmaxf(mx, __shfl_xor(mx, 1, 64));
    mx = fmaxf(mx, __shfl_xor(mx, 2, 64));

    float sum = 0.f;
#pragma unroll
    for (int c = 0; c < 13; c++) {
        f32x4 s = sv[c];
        s[0] = __expf(s[0] - mx); s[1] = __expf(s[1] - mx);
        s[2] = __expf(s[2] - mx); s[3] = __expf(s[3] - mx);
        sv[c] = s;
        sum += (s[0] + s[1]) + (s[2] + s[3]);
    }
    sum += __shfl_xor(sum, 1, 64);
    sum += __shfl_xor(sum, 2, 64);
    float inv = (sum > 0.f) ? 1.f / sum : 0.f;

    float* aop = attn_out + ((size_t)bh * 200 + irow) * 200;
#pragma unroll
    for (int c = 0; c < 13; c++) {
        int col = c * 16 + sub * 4;
        f32x4 a = sv[c];
        a[0] *= inv; a[1] *= inv; a[2] *= inv; a[3] *= inv;
        union { u16 q[4]; uint2 u; } pk;
        if (col < 200) {
            pk.q[0] = f2bf(a[0]); pk.q[1] = f2bf(a[1]);
            pk.q[2] = f2bf(a[2]); pk.q[3] = f2bf(a[3]);
        } else pk.u = make_uint2(0u, 0u);              // cols 200..207 zeroed for PV
        *(uint2*)&pb[row * 208 + col] = pk.u;
        if (rowok && col < 200)
            *(float4*)(aop + col) = make_float4(a[0], a[1], a[2], a[3]);
    }

    // ---- phase C: PV from LDS bf16 A-frags, global vt B-frags
    f32x4 ctx[4];
#pragma unroll
    for (int nt = 0; nt < 4; nt++) ctx[nt] = (f32x4){0.f, 0.f, 0.f, 0.f};
    const u16* vb = vtg + (size_t)bh * 64 * 200;
#pragma unroll
    for (int kc = 0; kc < 224; kc += 32) {
        int j0 = kc + quad * 8;
        bf16x8 af = (j0 < 208) ? load8(pb + l15 * 208 + j0) : bzero8();
#pragma unroll
        for (int nt = 0; nt < 4; nt++) {
            bf16x8 bvf = (j0 < 200) ? load8(vb + (nt * 16 + l15) * 200 + j0) : bzero8();
            ctx[nt] = MFMA16(af, bvf, ctx[nt]);
        }
    }

    // stage ctx (C layout) into pb, then coalesced uint4 copy-out
#pragma unroll
    for (int nt = 0; nt < 4; nt++)
#pragma unroll
        for (int r = 0; r < 4; r++)
            pb[(quad * 4 + r) * 208 + nt * 16 + l15] = f2bf(ctx[nt][r]);

#pragma unroll
    for (int k = 0; k < 2; k++) {
        int rr = k * 8 + (lane >> 3), ss = lane & 7;
        int ia = i0 + rr;
        uint4 val = *(const uint4*)&pb[rr * 208 + ss * 8];
        if (ia < 200)
            *(uint4*)&ctxb[((size_t)b * 200 + ia) * 1024 + h * 64 + ss * 8] = val;
    }
}

// ---- launch ----------------------------------------------------------------
extern "C" void kernel_launch(void* const* d_in, const int* in_sizes, int n_in,
                              void* d_out, int out_size, void* d_ws, size_t ws_size,
                              hipStream_t stream) {
    const float* x    = (const float*)d_in[0];
    const int*   mask = (const int*)d_in[1];
    const float* wq   = (const float*)d_in[2];
    const float* bq   = (const float*)d_in[3];
    const float* wk   = (const float*)d_in[4];
    const float* bk   = (const float*)d_in[5];
    const float* wv   = (const float*)d_in[6];
    const float* bv   = (const float*)d_in[7];
    const float* wo   = (const float*)d_in[8];
    const float* bo   = (const float*)d_in[9];
    const float* tb   = (const float*)d_in[10];

    float* out  = (float*)d_out;
    float* attn = out + OUT0_ELEMS;

    char* ws = (char*)d_ws;
    u16* xb    = (u16*)(ws);                    // 26,214,400 B
    u16* wqb   = (u16*)(ws + 26214400);         //  2,097,152 B
    u16* wkb   = (u16*)(ws + 28311552);
    u16* wvb   = (u16*)(ws + 30408704);
    u16* wob   = (u16*)(ws + 32505856);
    u16* qb    = (u16*)(ws + 34603008);         // 26,214,400 B  [b,h,s,dk]
    u16* kb    = (u16*)(ws + 60817408);         // 26,214,400 B
    u16* vtb   = (u16*)(ws + 87031808);         // 26,214,400 B  [b,h,dk,s]
    u16* ctxb  = (u16*)(ws + 113246208);        // 26,214,400 B  [b,s,h*dk]
    u64* mbits = (u64*)(ws + 139460608);        //    409,600 B  [b*200+i][4]
    // total: 139,870,208 B

    // 1) convert x + weights to bf16
    convert_k<<<dim3(16896), dim3(256), 0, stream>>>(x, wq, wk, wv, wo, xb, wqb, wkb, wvb, wob);

    // 1b) bit-pack mask: 12800 rows, 4 rows/block
    maskbits_k<<<dim3(3200), dim3(256), 0, stream>>>(mask, mbits);

    // 2) QKV projections
    gemm_k<0><<<dim3(8, 100, 3), dim3(256), 0, stream>>>(
        xb, wqb, wkb, wvb, bq, bk, bv, qb, kb, vtb, nullptr);

    // 3) fused attention: 4 row-tiles x (B*H = 1024)
    attn_k<<<dim3(4, 1024), dim3(256), 0, stream>>>(qb, kb, vtb, tb, mbits, attn, ctxb);

    // 4) output projection
    gemm_k<1><<<dim3(8, 100, 1), dim3(256), 0, stream>>>(
        ctxb, wob, nullptr, nullptr, bo, nullptr, nullptr, nullptr, nullptr, nullptr, out);
}

// Round 3
// 551.254 us; speedup vs baseline: 1.2070x; 1.0660x over previous
//
#include <hip/hip_runtime.h>
#include <stdint.h>

typedef unsigned short u16;
typedef unsigned long long u64;
typedef __bf16 bf16x8 __attribute__((ext_vector_type(8)));
typedef float f32x4 __attribute__((ext_vector_type(4)));

#define MFMA16(a, b, c) __builtin_amdgcn_mfma_f32_16x16x32_bf16((a), (b), (c), 0, 0, 0)

// ---- constants -------------------------------------------------------------
#define BB 64
#define SS 200
#define DM 1024
#define NH 16
#define MM (BB * SS)          // 12800
#define OUT0_ELEMS (MM * DM)  // 13107200

// ---- helpers ---------------------------------------------------------------
__device__ static inline u16 f2bf(float f) {
    __bf16 h = (__bf16)f;                 // RNE convert
    return __builtin_bit_cast(u16, h);
}

__device__ static inline bf16x8 load8(const u16* p) {
    uint4 u = *(const uint4*)p;           // 16B vector load
    union { uint4 u; bf16x8 b; } cv; cv.u = u; return cv.b;
}

__device__ static inline bf16x8 bzero8() {
    union { uint4 u; bf16x8 b; } cv; cv.u = make_uint4(0u, 0u, 0u, 0u); return cv.b;
}

__device__ static inline void gload_lds16(const void* g, void* l) {
    __builtin_amdgcn_global_load_lds(
        (const __attribute__((address_space(1))) void*)g,
        (__attribute__((address_space(3))) void*)l, 16, 0, 0);
}

// ---- kernel 1: f32 -> bf16 conversion (x + 4 weight matrices) --------------
__global__ __launch_bounds__(256) void convert_k(
    const float* __restrict__ x,
    const float* __restrict__ wq, const float* __restrict__ wk,
    const float* __restrict__ wv, const float* __restrict__ wo,
    u16* __restrict__ xb,
    u16* __restrict__ wqb, u16* __restrict__ wkb,
    u16* __restrict__ wvb, u16* __restrict__ wob)
{
    size_t i4 = (size_t)blockIdx.x * 256 + threadIdx.x;
    size_t e = i4 * 4;
    const float* src; u16* dst; size_t off;
    if (e < (size_t)OUT0_ELEMS) { src = x; dst = xb; off = e; }
    else {
        size_t we = e - OUT0_ELEMS;
        size_t w = we >> 20;              // each weight = 1048576 elems
        off = we & 1048575u;
        src = (w == 0) ? wq : (w == 1) ? wk : (w == 2) ? wv : wo;
        dst = (w == 0) ? wqb : (w == 1) ? wkb : (w == 2) ? wvb : wob;
    }
    float4 v = *(const float4*)(src + off);
    union { u16 s[4]; uint2 u; } o;
    o.s[0] = f2bf(v.x); o.s[1] = f2bf(v.y); o.s[2] = f2bf(v.z); o.s[3] = f2bf(v.w);
    *(uint2*)(dst + off) = o.u;
}

// ---- kernel 1b: mask [64,1,200,200] int32 -> bit-packed 4 u64 per row ------
__global__ __launch_bounds__(256) void maskbits_k(
    const int* __restrict__ mask, u64* __restrict__ bits)
{
    __shared__ unsigned char nb[4][64];
    const int wave = threadIdx.x >> 6, lane = threadIdx.x & 63;
    const int row = blockIdx.x * 4 + wave;       // 0..12799 = b*200 + i
    const int* mp = mask + (size_t)row * 200;
    unsigned nib;
    if (lane < 50) {
        int4 v = *(const int4*)(mp + lane * 4);
        nib = (v.x ? 1u : 0u) | (v.y ? 2u : 0u) | (v.z ? 4u : 0u) | (v.w ? 8u : 0u);
    } else nib = 0xFu;                           // cols >= 200: unmasked (never used)
    nb[wave][lane] = (unsigned char)nib;
    __builtin_amdgcn_s_waitcnt(0);               // same-wave LDS ordering
    if (lane < 4) {
        const unsigned char* p = &nb[wave][lane * 16];
        u64 m = 0;
#pragma unroll
        for (int i = 0; i < 16; i++) m |= (u64)(p[i] & 0xFu) << (4 * i);
        bits[(size_t)row * 4 + lane] = m;
    }
}

// ---- kernel 2/5: 128x128 MFMA GEMM, A[M,1024] bf16 * W[N,1024]^T ----------
// MODE 0: fused QKV, W = [wq;wk;wv] (3072 rows). seg = n0>>10 selects output:
//   q,k -> row-major bf16 [12800][1024] via LDS-staged coalesced uint4 stores
//   v   -> [b,h,dk,s] transposed (uint2 stores along s)
// MODE 1: out-proj; epilogue adds bias, writes f32 row-major [M,1024].
template <int MODE>
__global__ __launch_bounds__(256) void gemm_k(
    const u16* __restrict__ A, const u16* __restrict__ W,
    const float* __restrict__ b0, const float* __restrict__ b1, const float* __restrict__ b2,
    u16* __restrict__ qo, u16* __restrict__ ko, u16* __restrict__ vto,
    float* __restrict__ outf)
{
    __shared__ __align__(16) u16 sm[8192];  // As(4096) + Bs(4096); reused as C-stage
    u16* As = sm;
    u16* Bs = sm + 4096;

    const int tid  = threadIdx.x;
    const int wave = tid >> 6;
    const int lane = tid & 63;
    const int quad = lane >> 4;
    const int l15  = lane & 15;
    const int n0   = blockIdx.x * 128;        // MODE0: 0..3071, MODE1: 0..1023
    const int m0   = blockIdx.y * 128;
    const int seg  = (MODE == 0) ? (n0 >> 10) : 0;
    const int nn0  = n0 & 1023;
    const float* bias = (MODE == 1) ? b0 : (seg == 0 ? b0 : (seg == 1 ? b1 : b2));

    const int srow = wave * 16 + (lane >> 2); // row within a 64-row half
    const int sk8  = (lane & 3) * 8;          // k-elem offset 0/8/16/24
    const int wuni = __builtin_amdgcn_readfirstlane(wave);

    f32x4 acc[4][4];
#pragma unroll
    for (int i = 0; i < 4; i++)
#pragma unroll
        for (int j = 0; j < 4; j++) acc[i][j] = (f32x4){0.f, 0.f, 0.f, 0.f};

    const int wr = (wave >> 1) * 64;  // wave row offset in 128-tile
    const int wc = (wave & 1) * 64;   // wave col offset

    const u16* Ag = A + (size_t)m0 * 1024;
    const u16* Wg = W + (size_t)n0 * 1024;

    for (int kc = 0; kc < 1024; kc += 32) {
        __syncthreads();
#pragma unroll
        for (int r = 0; r < 2; r++) {
            int row = r * 64 + srow;
            gload_lds16(Ag + (size_t)row * 1024 + kc + sk8, &As[(r * 64 + wuni * 16) * 32]);
        }
#pragma unroll
        for (int r = 0; r < 2; r++) {
            int row = r * 64 + srow;
            gload_lds16(Wg + (size_t)row * 1024 + kc + sk8, &Bs[(r * 64 + wuni * 16) * 32]);
        }
        __syncthreads();

        bf16x8 af[4], bf[4];
#pragma unroll
        for (int mt = 0; mt < 4; mt++) af[mt] = load8(&As[(wr + mt * 16 + l15) * 32 + quad * 8]);
#pragma unroll
        for (int nt = 0; nt < 4; nt++) bf[nt] = load8(&Bs[(wc + nt * 16 + l15) * 32 + quad * 8]);
#pragma unroll
        for (int mt = 0; mt < 4; mt++)
#pragma unroll
            for (int nt = 0; nt < 4; nt++)
                acc[mt][nt] = MFMA16(af[mt], bf[nt], acc[mt][nt]);
    }

    // epilogue  (C layout: col = lane&15, row = quad*4 + reg)
    if (MODE == 1) {
#pragma unroll
        for (int nt = 0; nt < 4; nt++) {
            int n = n0 + wc + nt * 16 + l15;
            float bv = bias[n];
#pragma unroll
            for (int mt = 0; mt < 4; mt++)
#pragma unroll
                for (int r = 0; r < 4; r++) {
                    int m = m0 + wr + mt * 16 + quad * 4 + r;
                    outf[(size_t)m * 1024 + n] = acc[mt][nt][r] + bv;
                }
        }
    } else if (seg == 2) {
        // v: lane holds 4 consecutive m(=s) at fixed n -> one uint2 per (mt,nt).
#pragma unroll
        for (int nt = 0; nt < 4; nt++) {
            int nn = nn0 + wc + nt * 16 + l15;
            float bv = bias[nn];
            int hh = nn >> 6, d = nn & 63;
#pragma unroll
            for (int mt = 0; mt < 4; mt++) {
                int mbase = m0 + wr + mt * 16 + quad * 4;
                int b = mbase / 200, s = mbase - b * 200;   // 200%4==0: no crossing
                union { u16 q[4]; uint2 u; } pk;
#pragma unroll
                for (int r = 0; r < 4; r++) pk.q[r] = f2bf(acc[mt][nt][r] + bv);
                *(uint2*)&vto[((size_t)(b * 16 + hh) * 64 + d) * 200 + s] = pk.u;
            }
        }
    } else {
        // q/k: stage C through LDS (two 64-row halves), coalesced uint4 stores.
        u16* dst = (seg == 0) ? qo : ko;
        float bv[4];
#pragma unroll
        for (int nt = 0; nt < 4; nt++) bv[nt] = bias[nn0 + wc + nt * 16 + l15];
#pragma unroll
        for (int h2 = 0; h2 < 2; h2++) {
            __syncthreads();
            if ((wave >> 1) == h2) {
#pragma unroll
                for (int nt = 0; nt < 4; nt++)
#pragma unroll
                    for (int mt = 0; mt < 4; mt++)
#pragma unroll
                        for (int r = 0; r < 4; r++) {
                            int rl = mt * 16 + quad * 4 + r;
                            int c  = wc + nt * 16 + l15;
                            sm[rl * 128 + (c ^ ((rl & 7) << 4))] = f2bf(acc[mt][nt][r] + bv[nt]);
                        }
            }
            __syncthreads();
#pragma unroll
            for (int j = 0; j < 4; j++) {
                int idx = tid + j * 256;
                int rl = idx >> 4, c8 = (idx & 15) * 8;
                int c8s = c8 ^ ((rl & 7) << 4);
                uint4 vv = *(const uint4*)&sm[rl * 128 + c8s];
                *(uint4*)&dst[((size_t)(m0 + h2 * 64 + rl)) * 1024 + nn0 + c8] = vv;
            }
        }
    }
}

// ---- kernel 3: fused attention per (bh, 16-row wave tile) ------------------
// q,k row-major [b*200+s][1024] (col = h*64+d); vt [bh][d][s].
// Phase A: QK^T MFMA -> f32 LDS (C-layout transpose buffer)
// Phase B: row-linear lanes (4/row): analytic bias + bitmask + softmax,
//          coalesced float4 attn stores; bf16 P-tile -> LDS (aliases Sf)
// Phase C: PV MFMA from LDS A-frags + global vt B-frags; coalesced ctx out
__global__ __launch_bounds__(256) void attn_k(
    const u16* __restrict__ qg, const u16* __restrict__ kg, const u16* __restrict__ vtg,
    const u64* __restrict__ mbits,
    float* __restrict__ attn_out, u16* __restrict__ ctxb)
{
    // 13568 B/wave, 54272 B total -> 3 blocks/CU (12 waves).
    __shared__ __align__(16) float Sf[4][16 * 212];

    const int tid  = threadIdx.x;
    const int wave = tid >> 6;
    const int lane = tid & 63;
    const int quad = lane >> 4;
    const int l15  = lane & 15;
    const int bh   = blockIdx.y;
    const int b    = bh >> 4;
    const int h    = bh & 15;
    const int i0   = blockIdx.x * 64 + wave * 16;
    if (i0 >= 200) return;                            // wave-uniform; no barriers used

    float* sf = Sf[wave];
    u16*   pb = (u16*)sf;    // aliased: all uses are value-dependent on sf reads

    // ---- phase A: scores -> Sf (C layout: row = quad*4+r, col = t*16+l15)
    int qi = i0 + l15;
    const u16* qrow = qg + ((size_t)(b * 200 + (qi < 200 ? qi : 0))) * 1024 + h * 64;
    bf16x8 aq0, aq1;
    if (qi < 200) { aq0 = load8(qrow + quad * 8); aq1 = load8(qrow + 32 + quad * 8); }
    else          { aq0 = bzero8(); aq1 = bzero8(); }

#pragma unroll
    for (int t = 0; t < 13; t++) {
        int kj = t * 16 + l15;
        const u16* krow = kg + ((size_t)(b * 200 + (kj < 200 ? kj : 0))) * 1024 + h * 64;
        bf16x8 bk0, bk1;
        if (kj < 200) { bk0 = load8(krow + quad * 8); bk1 = load8(krow + 32 + quad * 8); }
        else          { bk0 = bzero8(); bk1 = bzero8(); }
        f32x4 z = (f32x4){0.f, 0.f, 0.f, 0.f};
        z = MFMA16(aq0, bk0, z);
        z = MFMA16(aq1, bk1, z);
#pragma unroll
        for (int r = 0; r < 4; r++) sf[(quad * 4 + r) * 212 + t * 16 + l15] = z[r];
    }

    // ---- phase B: row-linear (row = lane>>2, sub = lane&3; 4 lanes per row)
    const int row = lane >> 2, sub = lane & 3;
    const int iabs = i0 + row;
    const bool rowok = iabs < 200;
    const int irow = rowok ? iabs : 0;
    const u64* mb = mbits + ((size_t)b * 200 + irow) * 4;
    ulonglong2 mA = *(const ulonglong2*)mb;
    ulonglong2 mB = *(const ulonglong2*)(mb + 2);
    const float fi = (float)irow;
    const float TBC = -0.1f / 200.0f;                 // analytic temporal bias coeff

    f32x4 sv[13];
    float mx = -3.0e38f;
#pragma unroll
    for (int c = 0; c < 13; c++) {
        int col = c * 16 + sub * 4;
        f32x4 s = *(const f32x4*)&sf[row * 212 + col];
        if (rowok && col < 200) {
            u64 ch = (col < 64) ? mA.x : (col < 128) ? mA.y : (col < 192) ? mB.x : mB.y;
            int sh = col & 63;
            s[0] = s[0] * 0.125f + TBC * fabsf(fi - (float)(col + 0));
            s[1] = s[1] * 0.125f + TBC * fabsf(fi - (float)(col + 1));
            s[2] = s[2] * 0.125f + TBC * fabsf(fi - (float)(col + 2));
            s[3] = s[3] * 0.125f + TBC * fabsf(fi - (float)(col + 3));
            if (!((ch >> (sh + 0)) & 1)) s[0] = -1e9f;
            if (!((ch >> (sh + 1)) & 1)) s[1] = -1e9f;
            if (!((ch >> (sh + 2)) & 1)) s[2] = -1e9f;
            if (!((ch >> (sh + 3)) & 1)) s[3] = -1e9f;
        } else { s[0] = s[1] = s[2] = s[3] = -3.0e38f; }
        sv[c] = s;
        mx = fmaxf(mx, fmaxf(fmaxf(s[0], s[1]), fmaxf(s[2], s[3])));
    }
    mx = fmaxf(mx, __shfl_xor(mx, 1, 64));
    mx = fmaxf(mx, __shfl_xor(mx, 2, 64));

    float sum = 0.f;
#pragma unroll
    for (int c = 0; c < 13; c++) {
        f32x4 s = sv[c];
        s[0] = __expf(s[0] - mx); s[1] = __expf(s[1] - mx);
        s[2] = __expf(s[2] - mx); s[3] = __expf(s[3] - mx);
        sv[c] = s;
        sum += (s[0] + s[1]) + (s[2] + s[3]);
    }
    sum += __shfl_xor(sum, 1, 64);
    sum += __shfl_xor(sum, 2, 64);
    float inv = (sum > 0.f) ? 1.f / sum : 0.f;

    float* aop = attn_out + ((size_t)bh * 200 + irow) * 200;
#pragma unroll
    for (int c = 0; c < 13; c++) {
        int col = c * 16 + sub * 4;
        f32x4 a = sv[c];
        a[0] *= inv; a[1] *= inv; a[2] *= inv; a[3] *= inv;
        union { u16 q[4]; uint2 u; } pk;
        if (col < 200) {
            pk.q[0] = f2bf(a[0]); pk.q[1] = f2bf(a[1]);
            pk.q[2] = f2bf(a[2]); pk.q[3] = f2bf(a[3]);
        } else pk.u = make_uint2(0u, 0u);              // cols 200..207 zeroed for PV
        *(uint2*)&pb[row * 208 + col] = pk.u;
        if (rowok && col < 200)
            *(float4*)(aop + col) = make_float4(a[0], a[1], a[2], a[3]);
    }

    // ---- phase C: PV from LDS bf16 A-frags, global vt B-frags
    f32x4 ctx[4];
#pragma unroll
    for (int nt = 0; nt < 4; nt++) ctx[nt] = (f32x4){0.f, 0.f, 0.f, 0.f};
    const u16* vb = vtg + (size_t)bh * 64 * 200;
#pragma unroll
    for (int kc = 0; kc < 224; kc += 32) {
        int j0 = kc + quad * 8;
        bf16x8 af = (j0 < 208) ? load8(pb + l15 * 208 + j0) : bzero8();
#pragma unroll
        for (int nt = 0; nt < 4; nt++) {
            bf16x8 bvf = (j0 < 200) ? load8(vb + (nt * 16 + l15) * 200 + j0) : bzero8();
            ctx[nt] = MFMA16(af, bvf, ctx[nt]);
        }
    }

    // stage ctx (C layout) into pb, then coalesced uint4 copy-out
#pragma unroll
    for (int nt = 0; nt < 4; nt++)
#pragma unroll
        for (int r = 0; r < 4; r++)
            pb[(quad * 4 + r) * 208 + nt * 16 + l15] = f2bf(ctx[nt][r]);

#pragma unroll
    for (int k = 0; k < 2; k++) {
        int rr = k * 8 + (lane >> 3), ss = lane & 7;
        int ia = i0 + rr;
        uint4 val = *(const uint4*)&pb[rr * 208 + ss * 8];
        if (ia < 200)
            *(uint4*)&ctxb[((size_t)b * 200 + ia) * 1024 + h * 64 + ss * 8] = val;
    }
}

// ---- launch ----------------------------------------------------------------
extern "C" void kernel_launch(void* const* d_in, const int* in_sizes, int n_in,
                              void* d_out, int out_size, void* d_ws, size_t ws_size,
                              hipStream_t stream) {
    const float* x    = (const float*)d_in[0];
    const int*   mask = (const int*)d_in[1];
    const float* wq   = (const float*)d_in[2];
    const float* bq   = (const float*)d_in[3];
    const float* wk   = (const float*)d_in[4];
    const float* bk   = (const float*)d_in[5];
    const float* wv   = (const float*)d_in[6];
    const float* bv   = (const float*)d_in[7];
    const float* wo   = (const float*)d_in[8];
    const float* bo   = (const float*)d_in[9];

    float* out  = (float*)d_out;
    float* attn = out + OUT0_ELEMS;

    char* ws = (char*)d_ws;
    u16* xb    = (u16*)(ws);                    // 26,214,400 B
    u16* wqb   = (u16*)(ws + 26214400);         //  2,097,152 B  } contiguous ->
    u16* wkb   = (u16*)(ws + 28311552);         //               }  fused W [3072][1024]
    u16* wvb   = (u16*)(ws + 30408704);         //               }
    u16* wob   = (u16*)(ws + 32505856);
    u16* qb    = (u16*)(ws + 34603008);         // 26,214,400 B  [b*200+s][1024]
    u16* kb    = (u16*)(ws + 60817408);         // 26,214,400 B  [b*200+s][1024]
    u16* vtb   = (u16*)(ws + 87031808);         // 26,214,400 B  [b,h,dk,s]
    u16* ctxb  = (u16*)(ws + 113246208);        // 26,214,400 B  [b,s,h*dk]
    u64* mbits = (u64*)(ws + 139460608);        //    409,600 B  [b*200+i][4]
    // total: 139,870,208 B

    // 1) convert x + weights to bf16
    convert_k<<<dim3(16896), dim3(256), 0, stream>>>(x, wq, wk, wv, wo, xb, wqb, wkb, wvb, wob);

    // 1b) bit-pack mask
    maskbits_k<<<dim3(3200), dim3(256), 0, stream>>>(mask, mbits);

    // 2) fused QKV projection: N=3072 (24 tiles) x M=12800 (100 tiles)
    gemm_k<0><<<dim3(24, 100), dim3(256), 0, stream>>>(
        xb, wqb, bq, bk, bv, qb, kb, vtb, nullptr);

    // 3) fused attention: 4 row-tiles x (B*H = 1024)
    attn_k<<<dim3(4, 1024), dim3(256), 0, stream>>>(qb, kb, vtb, mbits, attn, ctxb);

    // 4) output projection
    gemm_k<1><<<dim3(8, 100), dim3(256), 0, stream>>>(
        ctxb, wob, bo, nullptr, nullptr, nullptr, nullptr, nullptr, out);
}